// Round 1
// baseline (12828.275 us; speedup 1.0000x reference)
//
#include <hip/hip_runtime.h>

// ---------------------------------------------------------------------------
// 3-layer LSTM (B=64, T=512, IN=128, H=1024) + final FC, persistent kernel.
//
// Architecture:
//  - 192 blocks x 256 threads (1 block/CU guaranteed by VGPR pressure), block
//    b: layer = b/64, owns hidden units [16*(b%64), +16) x 4 gates = 64 rows,
//    FULL K (layer0: 128+1024, layer1/2: 1024+1024), full batch 64.
//  - Weights held in registers as fp16 MFMA A-fragments for the whole kernel.
//  - Layers pipelined diagonally; one custom grid barrier per iteration
//    (514 iterations). h published to ws in MFMA B-fragment layout (fp16),
//    double-buffered by parity. c kept in fp32 thread registers.
//  - Cross-XCD visibility via __threadfence (L2 wb/inv) + agent-scope atomics.
// ---------------------------------------------------------------------------

#define TT 512
#define INF 128
#define HH 1024
#define NBLOCKS 192

typedef _Float16 f16x8 __attribute__((ext_vector_type(8)));
typedef float f32x4 __attribute__((ext_vector_type(4)));

// ws layout (bytes):
//   0       : ctrl[2]  (barrier count, generation)
//   1024    : hbuf  3 layers x 2 parity x 32 kk x 4 bt x 64 lane x 8 f16 = 786432 B
//   787456  : xbuf  512 t x 4 kk x 4 bt x 64 lane x 8 f16 = 8388608 B
#define HBUF_OFF 1024
#define XBUF_OFF (1024 + 786432)

__device__ __forceinline__ float sigmf(float x) { return 1.f / (1.f + __expf(-x)); }
__device__ __forceinline__ float tanhfast(float x) { return 1.f - 2.f / (__expf(2.f * x) + 1.f); }

__global__ void init_kernel(unsigned* ctrl, unsigned* hbuf_u32, float* out, const float* fcb) {
  int tid = blockIdx.x * 256 + threadIdx.x;
  if (tid < 196608) hbuf_u32[tid] = 0u;          // zero hbuf (786432 B)
  if (blockIdx.x == 0) {
    if (threadIdx.x < 2) ctrl[threadIdx.x] = 0u; // barrier state
    if (threadIdx.x >= 64 && threadIdx.x < 128) out[threadIdx.x - 64] = fcb[0];
  }
}

// Pack x[b][t][k] (fp32) -> fp16 B-fragment layout [t][kk][bt][lane][8]
__global__ void packx_kernel(const float* __restrict__ x, _Float16* __restrict__ xbuf) {
  int tid = blockIdx.x * 256 + threadIdx.x; // [0, 524288)
  int t = tid >> 10;
  int rem = tid & 1023;
  int kk = rem >> 8;
  int bt = (rem >> 6) & 3;
  int lane = rem & 63;
  int b = bt * 16 + (lane & 15);
  int k = kk * 32 + (lane >> 4) * 8;
  const float* src = x + ((size_t)b * TT + t) * INF + k;
  f16x8 v;
#pragma unroll
  for (int j = 0; j < 8; ++j) v[j] = (_Float16)src[j];
  ((f16x8*)xbuf)[tid] = v;
}

__global__ void __launch_bounds__(256, 1)
lstm_main(const float* __restrict__ Wih0, const float* __restrict__ Wih1,
          const float* __restrict__ Wih2, const float* __restrict__ Whh,
          const float* __restrict__ bih, const float* __restrict__ bhh,
          const float* __restrict__ fcw, float* __restrict__ out,
          unsigned* __restrict__ ctrl, _Float16* __restrict__ hbuf,
          const _Float16* __restrict__ xbuf) {
  const int blk = blockIdx.x;
  const int layer = blk >> 6;
  const int cu = blk & 63;
  const int tid = threadIdx.x;
  const int wave = tid >> 6;
  const int lane = tid & 63;
  const int m = lane & 15;   // A-frag row within 16
  const int q = lane >> 4;   // A/B-frag k-quad
  const int hid0 = cu << 4;  // 16 hidden units per CU

  const int KW = (layer == 0) ? 9 : 16;  // K-steps (32 wide) per wave
  const int kk0 = wave * KW;

  __shared__ float part[4][4][16][65];  // [wave][gate][j][batch] (+pad)
  __shared__ float fcacc[64];

  // ---- one-time: load weights into A-fragments (registers, fp16) ----
  f16x8 fz;
#pragma unroll
  for (int j = 0; j < 8; ++j) fz[j] = (_Float16)0.f;

  f16x8 afrag[4][16];
#pragma unroll
  for (int g = 0; g < 4; ++g) {
#pragma unroll
    for (int kkl = 0; kkl < 16; ++kkl) {
      afrag[g][kkl] = fz;
      if (kkl < KW) {
        int kk = kk0 + kkl;
        int row = g * HH + hid0 + m;
        const float* src;
        if (layer == 0) {
          src = (kk < 4) ? (Wih0 + (size_t)row * INF + kk * 32)
                         : (Whh + (size_t)row * HH + (kk - 4) * 32);
        } else if (layer == 1) {
          src = (kk < 32) ? (Wih1 + (size_t)row * HH + kk * 32)
                          : (Whh + (size_t)(4 * HH) * HH + (size_t)row * HH + (kk - 32) * 32);
        } else {
          src = (kk < 32) ? (Wih2 + (size_t)row * HH + kk * 32)
                          : (Whh + (size_t)(8 * HH) * HH + (size_t)row * HH + (kk - 32) * 32);
        }
        src += q * 8;
        f16x8 v;
#pragma unroll
        for (int j = 0; j < 8; ++j) v[j] = (_Float16)src[j];
        afrag[g][kkl] = v;
      }
    }
  }

  // ---- per-thread combine state: thread -> (j_l = tid&15, batches b0..b0+3)
  const int j_l = tid & 15;
  const int b0 = (tid >> 4) << 2;
  float biasv[4];
#pragma unroll
  for (int g = 0; g < 4; ++g) {
    int row = layer * 4 * HH + g * HH + hid0 + j_l;
    biasv[g] = bih[row] + bhh[row];
  }
  const float fcwv = (layer == 2) ? fcw[hid0 + j_l] : 0.f;
  float cst[4] = {0.f, 0.f, 0.f, 0.f};

  const f16x8* hb8 = (const f16x8*)hbuf;
  const f16x8* xb8 = (const f16x8*)xbuf;

  const f32x4 zacc = {0.f, 0.f, 0.f, 0.f};

  for (int s = 0; s < TT + 2; ++s) {
    const int t = s - layer;
    const bool active = (t >= 0) && (t < TT);
    if (active) {
      const int rp = (s + 1) & 1;  // read parity (written last iteration)
      const int wp = s & 1;        // write parity

      f32x4 acc[4][4];
#pragma unroll
      for (int g = 0; g < 4; ++g)
#pragma unroll
        for (int bt = 0; bt < 4; ++bt) acc[g][bt] = zacc;

#pragma unroll
      for (int kkl = 0; kkl < 16; ++kkl) {
        if (kkl < KW) {
          int kk = kk0 + kkl;
          const f16x8* bsrc;
          int kidx;
          if (layer == 0) {
            if (kk < 4) { bsrc = xb8 + (size_t)t * 1024; kidx = kk; }
            else        { bsrc = hb8 + (0 * 2 + rp) * 8192; kidx = kk - 4; }
          } else if (layer == 1) {
            if (kk < 32) { bsrc = hb8 + (0 * 2 + rp) * 8192; kidx = kk; }
            else         { bsrc = hb8 + (1 * 2 + rp) * 8192; kidx = kk - 32; }
          } else {
            if (kk < 32) { bsrc = hb8 + (1 * 2 + rp) * 8192; kidx = kk; }
            else         { bsrc = hb8 + (2 * 2 + rp) * 8192; kidx = kk - 32; }
          }
          f16x8 bf[4];
#pragma unroll
          for (int bt = 0; bt < 4; ++bt) bf[bt] = bsrc[kidx * 256 + bt * 64 + lane];
#pragma unroll
          for (int g = 0; g < 4; ++g)
#pragma unroll
            for (int bt = 0; bt < 4; ++bt)
              acc[g][bt] = __builtin_amdgcn_mfma_f32_16x16x32_f16(
                  afrag[g][kkl], bf[bt], acc[g][bt], 0, 0, 0);
        }
      }

      // partials -> LDS  (D layout: col=lane&15 (batch), row=q*4+r (j))
#pragma unroll
      for (int g = 0; g < 4; ++g)
#pragma unroll
        for (int bt = 0; bt < 4; ++bt)
#pragma unroll
          for (int r = 0; r < 4; ++r)
            part[wave][g][q * 4 + r][bt * 16 + m] = acc[g][bt][r];

      const bool do_fc = (layer == 2) && (t == TT - 1);
      if (do_fc && tid < 64) fcacc[tid] = 0.f;
      __syncthreads();

      // combine: sum 4 wave-partials, add bias, nonlinearity, update c, publish h
      float pre[4][4];
#pragma unroll
      for (int g = 0; g < 4; ++g)
#pragma unroll
        for (int i = 0; i < 4; ++i) pre[g][i] = biasv[g];
#pragma unroll
      for (int w = 0; w < 4; ++w)
#pragma unroll
        for (int g = 0; g < 4; ++g)
#pragma unroll
          for (int i = 0; i < 4; ++i) pre[g][i] += part[w][g][j_l][b0 + i];

      const int j = hid0 + j_l;
      const int kkp = j >> 5;
      const int qp = (j >> 3) & 3;
      const int byi = j & 7;
      _Float16* pubbase = hbuf + ((size_t)(((layer * 2 + wp) * 32 + kkp)) * 256) * 8;
#pragma unroll
      for (int i = 0; i < 4; ++i) {
        float ig = sigmf(pre[0][i]);
        float fg = sigmf(pre[1][i]);
        float gg = tanhfast(pre[2][i]);
        float og = sigmf(pre[3][i]);
        cst[i] = fg * cst[i] + ig * gg;
        float hv = og * tanhfast(cst[i]);
        int b = b0 + i;
        int btp = b >> 4;
        int lanep = (b & 15) + (qp << 4);
        pubbase[((size_t)(btp * 64 + lanep)) * 8 + byi] = (_Float16)hv;
        if (do_fc) atomicAdd(&fcacc[b], hv * fcwv);
      }
      if (do_fc) {
        __syncthreads();
        if (tid < 64) atomicAdd(&out[tid], fcacc[tid]);
      }
    }

    // ---- grid barrier (sense via generation counter, agent scope) ----
    __syncthreads();
    if (tid == 0) {
      __threadfence();  // release: drain stores, L2 writeback (agent scope)
      unsigned g0 = __hip_atomic_load(&ctrl[1], __ATOMIC_RELAXED, __HIP_MEMORY_SCOPE_AGENT);
      unsigned a = __hip_atomic_fetch_add(&ctrl[0], 1u, __ATOMIC_ACQ_REL, __HIP_MEMORY_SCOPE_AGENT);
      if (a == (unsigned)(NBLOCKS - 1)) {
        __hip_atomic_store(&ctrl[0], 0u, __ATOMIC_RELAXED, __HIP_MEMORY_SCOPE_AGENT);
        __hip_atomic_fetch_add(&ctrl[1], 1u, __ATOMIC_RELEASE, __HIP_MEMORY_SCOPE_AGENT);
      } else {
        while (__hip_atomic_load(&ctrl[1], __ATOMIC_RELAXED, __HIP_MEMORY_SCOPE_AGENT) == g0) {
          __builtin_amdgcn_s_sleep(8);
        }
      }
      __threadfence();  // acquire: invalidate L1/L2 so fresh h is visible
    }
    __syncthreads();
  }
}

extern "C" void kernel_launch(void* const* d_in, const int* in_sizes, int n_in,
                              void* d_out, int out_size, void* d_ws, size_t ws_size,
                              hipStream_t stream) {
  const float* x    = (const float*)d_in[0];
  const float* Wih0 = (const float*)d_in[1];
  const float* Wih1 = (const float*)d_in[2];
  const float* Wih2 = (const float*)d_in[3];
  const float* Whh  = (const float*)d_in[4];
  const float* bih  = (const float*)d_in[5];
  const float* bhh  = (const float*)d_in[6];
  const float* fcw  = (const float*)d_in[7];
  const float* fcb  = (const float*)d_in[8];
  float* out = (float*)d_out;

  char* ws = (char*)d_ws;
  unsigned* ctrl = (unsigned*)ws;
  _Float16* hbuf = (_Float16*)(ws + HBUF_OFF);
  _Float16* xbuf = (_Float16*)(ws + XBUF_OFF);

  init_kernel<<<768, 256, 0, stream>>>(ctrl, (unsigned*)hbuf, out, fcb);
  packx_kernel<<<2048, 256, 0, stream>>>(x, xbuf);
  lstm_main<<<NBLOCKS, 256, 0, stream>>>(Wih0, Wih1, Wih2, Whh, bih, bhh, fcw,
                                         out, ctrl, hbuf, xbuf);
}

// Round 2
// 7175.049 us; speedup vs baseline: 1.7879x; 1.7879x over previous
//
#include <hip/hip_runtime.h>

// ---------------------------------------------------------------------------
// 3-layer LSTM (B=64, T=512, IN=128, H=1024) + final FC, persistent kernel.
//
// R2: removed ALL L2 cache-maintenance ops (threadfence / acq-rel atomics).
//  - h traffic: RELAXED agent-scope 8B atomics (sc1, L2-bypass, IC-coherent).
//  - barrier: single monotonic counter, all-relaxed, spin on cnt >= target.
//  - combine remapped: thread owns (1 batch x 4 consecutive j) -> one 8B
//    aligned publish store per thread.
//  - LDS pad 66 (2-way bank aliasing = free), B-frag prefetch pipeline.
// ---------------------------------------------------------------------------

#define TT 512
#define INF 128
#define HH 1024
#define NBLOCKS 192

typedef _Float16 f16x8 __attribute__((ext_vector_type(8)));
typedef float f32x4 __attribute__((ext_vector_type(4)));

// ws layout (bytes):
//   0       : ctrl[2]  (barrier monotonic counter, unused)
//   1024    : hbuf  3 layers x 2 parity x 32 kk x 4 bt x 64 lane x 8 f16 = 786432 B
//   787456  : xbuf  512 t x 4 kk x 4 bt x 64 lane x 8 f16 = 8388608 B
#define HBUF_OFF 1024
#define XBUF_OFF (1024 + 786432)

__device__ __forceinline__ float sigmf(float x) { return 1.f / (1.f + __expf(-x)); }
__device__ __forceinline__ float tanhfast(float x) { return 1.f - 2.f / (__expf(2.f * x) + 1.f); }

__global__ void init_kernel(unsigned* ctrl, unsigned* hbuf_u32, float* out, const float* fcb) {
  int tid = blockIdx.x * 256 + threadIdx.x;
  if (tid < 196608) hbuf_u32[tid] = 0u;          // zero hbuf (786432 B)
  if (blockIdx.x == 0) {
    if (threadIdx.x < 2) ctrl[threadIdx.x] = 0u; // barrier state
    if (threadIdx.x >= 64 && threadIdx.x < 128) out[threadIdx.x - 64] = fcb[0];
  }
}

// Pack x[b][t][k] (fp32) -> fp16 B-fragment layout [t][kk][bt][lane][8]
__global__ void packx_kernel(const float* __restrict__ x, _Float16* __restrict__ xbuf) {
  int tid = blockIdx.x * 256 + threadIdx.x; // [0, 524288)
  int t = tid >> 10;
  int rem = tid & 1023;
  int kk = rem >> 8;
  int bt = (rem >> 6) & 3;
  int lane = rem & 63;
  int b = bt * 16 + (lane & 15);
  int k = kk * 32 + (lane >> 4) * 8;
  const float* src = x + ((size_t)b * TT + t) * INF + k;
  f16x8 v;
#pragma unroll
  for (int j = 0; j < 8; ++j) v[j] = (_Float16)src[j];
  ((f16x8*)xbuf)[tid] = v;
}

// Agent-coherent (IC-level) 16B fragment load as two relaxed 8B atomics.
__device__ __forceinline__ f16x8 load_frag_agent(const unsigned long long* p) {
  union { unsigned long long u[2]; f16x8 v; } r;
  r.u[0] = __hip_atomic_load(p, __ATOMIC_RELAXED, __HIP_MEMORY_SCOPE_AGENT);
  r.u[1] = __hip_atomic_load(p + 1, __ATOMIC_RELAXED, __HIP_MEMORY_SCOPE_AGENT);
  return r.v;
}

// Load the 4 bt B-fragments for global k-chunk kk.
__device__ __forceinline__ void loadB(f16x8 bf[4], int layer, int kk, int t, int rp,
                                      const f16x8* __restrict__ xb8,
                                      const unsigned long long* __restrict__ hb_u,
                                      int lane) {
  if (layer == 0 && kk < 4) {
    const f16x8* bsrc = xb8 + (size_t)t * 1024 + (size_t)kk * 256;
#pragma unroll
    for (int bt = 0; bt < 4; ++bt) bf[bt] = bsrc[bt * 64 + lane];
  } else {
    int buf, kidx;
    if (layer == 0) { buf = rp; kidx = kk - 4; }
    else if (layer == 1) {
      if (kk < 32) { buf = rp; kidx = kk; } else { buf = 2 + rp; kidx = kk - 32; }
    } else {
      if (kk < 32) { buf = 2 + rp; kidx = kk; } else { buf = 4 + rp; kidx = kk - 32; }
    }
#pragma unroll
    for (int bt = 0; bt < 4; ++bt)
      bf[bt] = load_frag_agent(hb_u + ((size_t)buf * 8192 + kidx * 256 + bt * 64 + lane) * 2);
  }
}

__global__ void __launch_bounds__(256, 1)
lstm_main(const float* __restrict__ Wih0, const float* __restrict__ Wih1,
          const float* __restrict__ Wih2, const float* __restrict__ Whh,
          const float* __restrict__ bih, const float* __restrict__ bhh,
          const float* __restrict__ fcw, float* __restrict__ out,
          unsigned* __restrict__ ctrl, _Float16* __restrict__ hbuf,
          const _Float16* __restrict__ xbuf) {
  const int blk = blockIdx.x;
  const int layer = blk >> 6;
  const int cu = blk & 63;
  const int tid = threadIdx.x;
  const int wave = tid >> 6;
  const int lane = tid & 63;
  const int m = lane & 15;   // A-frag row within 16 (j), D-frag col (batch)
  const int q = lane >> 4;   // k-quad
  const int hid0 = cu << 4;  // 16 hidden units per block

  const int KW = (layer == 0) ? 9 : 16;  // K-steps (32 wide) per wave
  const int kk0 = wave * KW;

  __shared__ float part[4][4][16][66];  // [wave][gate][j][batch], pad 66 (2-way free)
  __shared__ float fcacc[64];

  // ---- one-time: load weights into A-fragments (registers, fp16) ----
  f16x8 fz;
#pragma unroll
  for (int j = 0; j < 8; ++j) fz[j] = (_Float16)0.f;

  f16x8 afrag[4][16];
#pragma unroll
  for (int g = 0; g < 4; ++g) {
#pragma unroll
    for (int kkl = 0; kkl < 16; ++kkl) {
      afrag[g][kkl] = fz;
      if (kkl < KW) {
        int kk = kk0 + kkl;
        int row = g * HH + hid0 + m;
        const float* src;
        if (layer == 0) {
          src = (kk < 4) ? (Wih0 + (size_t)row * INF + kk * 32)
                         : (Whh + (size_t)row * HH + (kk - 4) * 32);
        } else if (layer == 1) {
          src = (kk < 32) ? (Wih1 + (size_t)row * HH + kk * 32)
                          : (Whh + (size_t)(4 * HH) * HH + (size_t)row * HH + (kk - 32) * 32);
        } else {
          src = (kk < 32) ? (Wih2 + (size_t)row * HH + kk * 32)
                          : (Whh + (size_t)(8 * HH) * HH + (size_t)row * HH + (kk - 32) * 32);
        }
        src += q * 8;
        f16x8 v;
#pragma unroll
        for (int j = 0; j < 8; ++j) v[j] = (_Float16)src[j];
        afrag[g][kkl] = v;
      }
    }
  }

  // ---- combine mapping: thread -> (batch bq = tid&63, j in [j4, j4+4)) ----
  const int bq = tid & 63;
  const int j4 = wave * 4;  // wave w combines j rows 4w..4w+3 (within the 16)
  float biasv[4][4];        // [gate][i]
#pragma unroll
  for (int g = 0; g < 4; ++g)
#pragma unroll
    for (int i = 0; i < 4; ++i) {
      int row = layer * 4 * HH + g * HH + hid0 + j4 + i;
      biasv[g][i] = bih[row] + bhh[row];
    }
  float fcwv[4];
#pragma unroll
  for (int i = 0; i < 4; ++i) fcwv[i] = (layer == 2) ? fcw[hid0 + j4 + i] : 0.f;
  float cst[4] = {0.f, 0.f, 0.f, 0.f};

  // publish address (all 4 j's of this thread share kkp/qp/8B-slot)
  const int jg = hid0 + j4;
  const int kkp = jg >> 5;
  const int qp = (jg >> 3) & 3;
  const int slot = (j4 & 7) >> 2;  // 0 or 1: which 8B half of the 16B chunk
  const int btp = bq >> 4;
  const int lanep = (bq & 15) + (qp << 4);

  const f16x8* xb8 = (const f16x8*)xbuf;
  const unsigned long long* hb_u = (const unsigned long long*)hbuf;
  unsigned long long* hb_w = (unsigned long long*)hbuf;

  const f32x4 zacc = {0.f, 0.f, 0.f, 0.f};

  for (int s = 0; s < TT + 2; ++s) {
    const int t = s - layer;
    const bool active = (t >= 0) && (t < TT);
    if (active) {
      const int rp = (s + 1) & 1;  // read parity (written last iteration)
      const int wp = s & 1;        // write parity

      f32x4 acc[4][4];
#pragma unroll
      for (int g = 0; g < 4; ++g)
#pragma unroll
        for (int bt = 0; bt < 4; ++bt) acc[g][bt] = zacc;

      // ---- K loop with one-stage B prefetch ----
      f16x8 bcur[4], bnxt[4];
      loadB(bcur, layer, kk0, t, rp, xb8, hb_u, lane);
#pragma unroll
      for (int kkl = 0; kkl < 16; ++kkl) {
        if (kkl < KW) {
          if (kkl + 1 < KW) loadB(bnxt, layer, kk0 + kkl + 1, t, rp, xb8, hb_u, lane);
#pragma unroll
          for (int g = 0; g < 4; ++g)
#pragma unroll
            for (int bt = 0; bt < 4; ++bt)
              acc[g][bt] = __builtin_amdgcn_mfma_f32_16x16x32_f16(
                  afrag[g][kkl], bcur[bt], acc[g][bt], 0, 0, 0);
#pragma unroll
          for (int bt = 0; bt < 4; ++bt) bcur[bt] = bnxt[bt];
        }
      }

      // partials -> LDS  (D layout: col=lane&15 (batch), row=q*4+r (j))
#pragma unroll
      for (int g = 0; g < 4; ++g)
#pragma unroll
        for (int bt = 0; bt < 4; ++bt)
#pragma unroll
          for (int r = 0; r < 4; ++r)
            part[wave][g][q * 4 + r][bt * 16 + m] = acc[g][bt][r];

      const bool do_fc = (layer == 2) && (t == TT - 1);
      if (do_fc && tid < 64) fcacc[tid] = 0.f;
      __syncthreads();

      // combine: sum 4 wave-partials, bias, nonlinearity, c update, publish h
      float pre[4][4];
#pragma unroll
      for (int g = 0; g < 4; ++g)
#pragma unroll
        for (int i = 0; i < 4; ++i) pre[g][i] = biasv[g][i];
#pragma unroll
      for (int w = 0; w < 4; ++w)
#pragma unroll
        for (int g = 0; g < 4; ++g)
#pragma unroll
          for (int i = 0; i < 4; ++i) pre[g][i] += part[w][g][j4 + i][bq];

      union { unsigned long long u; _Float16 h4[4]; } pk;
      float facc = 0.f;
#pragma unroll
      for (int i = 0; i < 4; ++i) {
        float ig = sigmf(pre[0][i]);
        float fg = sigmf(pre[1][i]);
        float gg = tanhfast(pre[2][i]);
        float og = sigmf(pre[3][i]);
        cst[i] = fg * cst[i] + ig * gg;
        float hv = og * tanhfast(cst[i]);
        pk.h4[i] = (_Float16)hv;
        facc += hv * fcwv[i];
      }
      unsigned long long* pub =
          hb_w + ((size_t)(((layer * 2 + wp) * 32 + kkp) * 256 + btp * 64 + lanep)) * 2 + slot;
      __hip_atomic_store(pub, pk.u, __ATOMIC_RELAXED, __HIP_MEMORY_SCOPE_AGENT);

      if (do_fc) {
        atomicAdd(&fcacc[bq], facc);
        __syncthreads();
        if (tid < 64) atomicAdd(&out[tid], fcacc[tid]);
      }
    }

    // ---- grid barrier: all-relaxed monotonic counter (no cache flushes) ----
    __builtin_amdgcn_s_waitcnt(0);  // each wave drains its publish stores to IC
    __syncthreads();                // all waves drained before tid0 signals
    if (tid == 0) {
      const unsigned target = (unsigned)(s + 1) * NBLOCKS;
      __hip_atomic_fetch_add(&ctrl[0], 1u, __ATOMIC_RELAXED, __HIP_MEMORY_SCOPE_AGENT);
      while (__hip_atomic_load(&ctrl[0], __ATOMIC_RELAXED, __HIP_MEMORY_SCOPE_AGENT) < target) {
        __builtin_amdgcn_s_sleep(2);
      }
    }
    __syncthreads();
  }
}

extern "C" void kernel_launch(void* const* d_in, const int* in_sizes, int n_in,
                              void* d_out, int out_size, void* d_ws, size_t ws_size,
                              hipStream_t stream) {
  const float* x    = (const float*)d_in[0];
  const float* Wih0 = (const float*)d_in[1];
  const float* Wih1 = (const float*)d_in[2];
  const float* Wih2 = (const float*)d_in[3];
  const float* Whh  = (const float*)d_in[4];
  const float* bih  = (const float*)d_in[5];
  const float* bhh  = (const float*)d_in[6];
  const float* fcw  = (const float*)d_in[7];
  const float* fcb  = (const float*)d_in[8];
  float* out = (float*)d_out;

  char* ws = (char*)d_ws;
  unsigned* ctrl = (unsigned*)ws;
  _Float16* hbuf = (_Float16*)(ws + HBUF_OFF);
  _Float16* xbuf = (_Float16*)(ws + XBUF_OFF);

  init_kernel<<<768, 256, 0, stream>>>(ctrl, (unsigned*)hbuf, out, fcb);
  packx_kernel<<<2048, 256, 0, stream>>>(x, xbuf);
  lstm_main<<<NBLOCKS, 256, 0, stream>>>(Wih0, Wih1, Wih2, Whh, bih, bhh, fcw,
                                         out, ctrl, hbuf, xbuf);
}